// Round 8
// baseline (953.900 us; speedup 1.0000x reference)
//
#include <hip/hip_runtime.h>

#define HID 128
#define BN_EPS 1e-5f
#define PSHIFT 9
#define PBW 512

typedef __bf16 bf16;
typedef __attribute__((ext_vector_type(8))) __bf16 bf16x8;
typedef __attribute__((ext_vector_type(2))) __bf16 bf16x2;
typedef __attribute__((ext_vector_type(4))) float f32x4;

__device__ __forceinline__ float bnrelu(float x, float a, float c) {
  return fmaxf(fmaf(a, x, c), 0.f);
}

// ---------------- per-node histogram ----------------
__global__ void hist_k(const int* __restrict__ dst, int* __restrict__ cnt, int E) {
  int i = blockIdx.x * blockDim.x + threadIdx.x;
  if (i < E) atomicAdd(&cnt[dst[i]], 1);
}

// block partial sums (1024 elems / block)
__global__ __launch_bounds__(256)
void scan1_k(const int* __restrict__ cnt, int* __restrict__ bsum, int Nn) {
  __shared__ int red[4];
  int tid = threadIdx.x;
  int base = blockIdx.x * 1024;
  int s = 0;
#pragma unroll
  for (int u = 0; u < 4; ++u) {
    int i = base + u * 256 + tid;
    if (i < Nn) s += cnt[i];
  }
#pragma unroll
  for (int d = 1; d < 64; d <<= 1) s += __shfl_xor(s, d, 64);
  int lane = tid & 63, wv = tid >> 6;
  if (lane == 0) red[wv] = s;
  __syncthreads();
  if (tid == 0) bsum[blockIdx.x] = red[0] + red[1] + red[2] + red[3];
}

// exclusive scan of block sums, in place (single wave)
__global__ void scan2_k(int* __restrict__ bsum, int G) {
  int lane = threadIdx.x;
  int carry = 0;
  for (int base = 0; base < G; base += 64) {
    int i = base + lane;
    int v = (i < G) ? bsum[i] : 0;
    int x = v;
#pragma unroll
    for (int d = 1; d < 64; d <<= 1) { int t = __shfl_up(x, d, 64); if (lane >= d) x += t; }
    if (i < G) bsum[i] = carry + x - v;
    carry += __shfl(x, 63, 64);
  }
}

// final scan: row_start
__global__ __launch_bounds__(256)
void scan3_k(const int* __restrict__ cnt, const int* __restrict__ boff,
             int* __restrict__ row_start, int Nn, int E) {
  __shared__ int wtot[4];
  int tid = threadIdx.x, lane = tid & 63, wv = tid >> 6;
  int i0 = blockIdx.x * 1024 + tid * 4;
  int t0 = 0, t1 = 0, t2 = 0, t3 = 0;
  if (i0 + 3 < Nn) {
    int4 v = *(const int4*)(cnt + i0);
    t0 = v.x; t1 = v.y; t2 = v.z; t3 = v.w;
  } else {
    if (i0     < Nn) t0 = cnt[i0];
    if (i0 + 1 < Nn) t1 = cnt[i0 + 1];
    if (i0 + 2 < Nn) t2 = cnt[i0 + 2];
    if (i0 + 3 < Nn) t3 = cnt[i0 + 3];
  }
  int tsum = t0 + t1 + t2 + t3;
  int x = tsum;
#pragma unroll
  for (int d = 1; d < 64; d <<= 1) { int t = __shfl_up(x, d, 64); if (lane >= d) x += t; }
  if (lane == 63) wtot[wv] = x;
  __syncthreads();
  int wo = 0;
  for (int k = 0; k < wv; ++k) wo += wtot[k];
  int base = boff[blockIdx.x] + wo + x - tsum;
  if (i0     < Nn) row_start[i0] = base;
  if (i0 + 1 < Nn) row_start[i0 + 1] = base + t0;
  if (i0 + 2 < Nn) row_start[i0 + 2] = base + t0 + t1;
  if (i0 + 3 < Nn) row_start[i0 + 3] = base + t0 + t1 + t2;
  if (blockIdx.x == 0 && tid == 0) row_start[Nn] = E;
}

// ---------------- coarse-bucket cursor init (bucket = PBW nodes) ----------------
__global__ void initb_k(const int* __restrict__ row_start, int* __restrict__ bcur,
                        int Nn, int NB2) {
  int i = threadIdx.x;
  if (i < NB2) {
    int n = i << PSHIFT; if (n > Nn) n = Nn;
    bcur[i] = row_start[n];
  }
}

// ---------------- partition edges into PBW-node buckets, packed (dl<<17)|src ----------------
__global__ __launch_bounds__(256)
void partb_k(const int* __restrict__ src, const int* __restrict__ dst,
             int* __restrict__ bcur, unsigned* __restrict__ ebuf2, int E, int NB2) {
  __shared__ int lcnt[256], gbase[256], lcur[256];
  int tid = threadIdx.x;
  if (tid < NB2 || tid < 256) { lcnt[tid] = 0; lcur[tid] = 0; }
  __syncthreads();
  int base = blockIdx.x * 2048;
  int ok[8]; unsigned pk[8]; int bk[8];
#pragma unroll
  for (int u = 0; u < 8; ++u) {
    int e = base + u * 256 + tid;
    if (e < E) {
      int s = src[e], d = dst[e];
      ok[u] = 1; bk[u] = d >> PSHIFT;
      pk[u] = ((unsigned)(d & (PBW - 1)) << 17) | (unsigned)s;
      atomicAdd(&lcnt[bk[u]], 1);
    } else ok[u] = 0;
  }
  __syncthreads();
  if (tid < NB2 && lcnt[tid]) gbase[tid] = atomicAdd(&bcur[tid], lcnt[tid]);
  __syncthreads();
#pragma unroll
  for (int u = 0; u < 8; ++u) if (ok[u]) {
    int sl = atomicAdd(&lcur[bk[u]], 1);
    ebuf2[gbase[bk[u]] + sl] = pk[u];
  }
}

// ---------------- bucket -> CSR (one block owns one PBW-node bucket) ----------------
__global__ __launch_bounds__(512)
void fillb_k(const unsigned* __restrict__ ebuf2, const int* __restrict__ row_start,
             int* __restrict__ csr, int Nn) {
  __shared__ int ncur[PBW];
  int tid = threadIdx.x;
  if (tid < PBW) ncur[tid] = 0;
  __syncthreads();
  int nb0 = blockIdx.x << PSHIFT;
  int hi = nb0 + PBW; if (hi > Nn) hi = Nn;
  int beg = row_start[nb0], end = row_start[hi];
  for (int e = beg + tid; e < end; e += 512) {
    unsigned v = ebuf2[e];
    int dl = v >> 17, s = (int)(v & 0x1FFFF);
    int p = atomicAdd(&ncur[dl], 1);
    csr[row_start[nb0 + dl] + p] = s;
  }
}

// ---------------- weight convert to bf16 ----------------
__global__ __launch_bounds__(256)
void wconv_k(const float* __restrict__ W0, const float* __restrict__ W1,
             const float* __restrict__ pW1, const float* __restrict__ pW2,
             bf16* __restrict__ Wb) {
  int idx = (blockIdx.x * 256 + threadIdx.x) * 4;
  int seg = idx >> 14, loc = idx & 16383;
  const float* srcp = seg < 3 ? W0 + (size_t)seg * 16384
                    : seg < 6 ? W1 + (size_t)(seg - 3) * 16384
                    : seg == 6 ? pW1 : pW2;
  float4 v = *(const float4*)(srcp + loc);
  union { bf16 h[4]; unsigned long long u; } pk;
  pk.h[0] = (bf16)v.x; pk.h[1] = (bf16)v.y; pk.h[2] = (bf16)v.z; pk.h[3] = (bf16)v.w;
  *(unsigned long long*)(Wb + idx) = pk.u;
}

// ---------------- x -> bf16 convert ----------------
__global__ __launch_bounds__(256)
void xconv_k(const float* __restrict__ X, bf16* __restrict__ Xh, int total) {
  int idx = (blockIdx.x * 256 + threadIdx.x) * 4;
  if (idx >= total) return;
  float4 v = *(const float4*)(X + idx);
  union { bf16 h[4]; unsigned long long u; } pk;
  pk.h[0] = (bf16)v.x; pk.h[1] = (bf16)v.y; pk.h[2] = (bf16)v.z; pk.h[3] = (bf16)v.w;
  *(unsigned long long*)(Xh + idx) = pk.u;
}

// ---------------- aggregation from bf16 source, unroll-8 ----------------
template<int MODE>
__global__ __launch_bounds__(256)
void agg_k(const bf16* __restrict__ Hh,
           const float* __restrict__ ac, const float* __restrict__ g, const float* __restrict__ b,
           float invN,
           const int* __restrict__ row_start, const int* __restrict__ csr,
           bf16* __restrict__ Z, int Nn) {
  __shared__ float sA[128], sC[128];
  int tid = threadIdx.x;
  if (MODE) {
    if (tid < 128) {
      float mu = ac[tid] * invN;
      float var = fmaxf(ac[128 + tid] * invN - mu * mu, 0.f);
      float a = g[tid] * rsqrtf(var + BN_EPS);
      sA[tid] = a; sC[tid] = fmaf(-a, mu, b[tid]);
    }
    __syncthreads();
  }
  int wv = tid >> 6, lane = tid & 63;
  int n = blockIdx.x * 4 + wv;
  if (n >= Nn) return;
  int c0 = lane * 2;
  float Ax = 0, Ay = 0, Cx = 0, Cy = 0;
  if (MODE) { Ax = sA[c0]; Ay = sA[c0 + 1]; Cx = sC[c0]; Cy = sC[c0 + 1]; }
  int beg = row_start[n], end = row_start[n + 1];
  bf16x2 hn = *(const bf16x2*)(Hh + (size_t)n * HID + c0);
  float inv = 1.f / fmaxf((float)(end - beg), 1.f);
  float ax0 = 0, ay0 = 0, ax1 = 0, ay1 = 0, ax2 = 0, ay2 = 0, ax3 = 0, ay3 = 0;
  int j = beg;
  for (; j + 8 <= end; j += 8) {
    int s0 = csr[j], s1 = csr[j + 1], s2 = csr[j + 2], s3 = csr[j + 3];
    int s4 = csr[j + 4], s5 = csr[j + 5], s6 = csr[j + 6], s7 = csr[j + 7];
    bf16x2 v0 = *(const bf16x2*)(Hh + (size_t)s0 * HID + c0);
    bf16x2 v1 = *(const bf16x2*)(Hh + (size_t)s1 * HID + c0);
    bf16x2 v2 = *(const bf16x2*)(Hh + (size_t)s2 * HID + c0);
    bf16x2 v3 = *(const bf16x2*)(Hh + (size_t)s3 * HID + c0);
    bf16x2 v4 = *(const bf16x2*)(Hh + (size_t)s4 * HID + c0);
    bf16x2 v5 = *(const bf16x2*)(Hh + (size_t)s5 * HID + c0);
    bf16x2 v6 = *(const bf16x2*)(Hh + (size_t)s6 * HID + c0);
    bf16x2 v7 = *(const bf16x2*)(Hh + (size_t)s7 * HID + c0);
    float x0 = (float)v0[0], y0 = (float)v0[1], x1 = (float)v1[0], y1 = (float)v1[1];
    float x2 = (float)v2[0], y2 = (float)v2[1], x3 = (float)v3[0], y3 = (float)v3[1];
    float x4 = (float)v4[0], y4 = (float)v4[1], x5 = (float)v5[0], y5 = (float)v5[1];
    float x6 = (float)v6[0], y6 = (float)v6[1], x7 = (float)v7[0], y7 = (float)v7[1];
    if (MODE) {
      x0 = bnrelu(x0, Ax, Cx); y0 = bnrelu(y0, Ay, Cy);
      x1 = bnrelu(x1, Ax, Cx); y1 = bnrelu(y1, Ay, Cy);
      x2 = bnrelu(x2, Ax, Cx); y2 = bnrelu(y2, Ay, Cy);
      x3 = bnrelu(x3, Ax, Cx); y3 = bnrelu(y3, Ay, Cy);
      x4 = bnrelu(x4, Ax, Cx); y4 = bnrelu(y4, Ay, Cy);
      x5 = bnrelu(x5, Ax, Cx); y5 = bnrelu(y5, Ay, Cy);
      x6 = bnrelu(x6, Ax, Cx); y6 = bnrelu(y6, Ay, Cy);
      x7 = bnrelu(x7, Ax, Cx); y7 = bnrelu(y7, Ay, Cy);
    }
    ax0 += x0; ay0 += y0; ax1 += x1; ay1 += y1;
    ax2 += x2; ay2 += y2; ax3 += x3; ay3 += y3;
    ax0 += x4; ay0 += y4; ax1 += x5; ay1 += y5;
    ax2 += x6; ay2 += y6; ax3 += x7; ay3 += y7;
  }
  for (; j < end; ++j) {
    int s = csr[j];
    bf16x2 v = *(const bf16x2*)(Hh + (size_t)s * HID + c0);
    float vx = (float)v[0], vy = (float)v[1];
    if (MODE) { vx = bnrelu(vx, Ax, Cx); vy = bnrelu(vy, Ay, Cy); }
    ax0 += vx; ay0 += vy;
  }
  float ax = (ax0 + ax1) + (ax2 + ax3);
  float ay = (ay0 + ay1) + (ay2 + ay3);
  float hx = (float)hn[0], hy = (float)hn[1];
  if (MODE) { hx = bnrelu(hx, Ax, Cx); hy = bnrelu(hy, Ay, Cy); }
  float zx = hx + ax * inv, zy = hy + ay * inv;
  union { bf16 h[2]; unsigned u; } pk;
  pk.h[0] = (bf16)zx; pk.h[1] = (bf16)zy;
  *(unsigned*)((char*)Z + ((size_t)n * HID + c0) * 2) = pk.u;
}

// ---------------- GEMM: C = A @ W^T, bf16 A and weights, fused column stats ----------------
template<int AMODE, int OUTF>
__global__ __launch_bounds__(256)
void gemm_k(const bf16* __restrict__ Asrc,
            const float* __restrict__ acIn, const float* __restrict__ g, const float* __restrict__ b,
            float invN,
            const bf16* __restrict__ Wb, bf16* __restrict__ Cb, float* __restrict__ Cf,
            float* __restrict__ accumOut, int Nrows) {
  __shared__ float sA[128], sC[128], sSum[128], sSq[128];
  int tid = threadIdx.x;
  if (tid < 128) {
    sSum[tid] = 0.f; sSq[tid] = 0.f;
    if (AMODE) {
      float mu = acIn[tid] * invN;
      float var = fmaxf(acIn[128 + tid] * invN - mu * mu, 0.f);
      float a = g[tid] * rsqrtf(var + BN_EPS);
      sA[tid] = a; sC[tid] = fmaf(-a, mu, b[tid]);
    }
  }
  __syncthreads();
  int wv = tid >> 6, lane = tid & 63;
  int lm = lane & 15, lg = lane >> 4;
  int rowbase = blockIdx.x * 128 + wv * 32;
  f32x4 acc[2][8] = {};
#pragma unroll
  for (int kk = 0; kk < 4; ++kk) {
    int kb = kk * 32 + lg * 8;
    bf16x8 af[2];
#pragma unroll
    for (int rt = 0; rt < 2; ++rt) {
      int row = rowbase + rt * 16 + lm; if (row > Nrows - 1) row = Nrows - 1;
      bf16x8 raw = *(const bf16x8*)(Asrc + (size_t)row * HID + kb);
      if (AMODE == 0) {
        af[rt] = raw;
      } else {
        float4 a0 = *(const float4*)(sA + kb), a1 = *(const float4*)(sA + kb + 4);
        float4 q0 = *(const float4*)(sC + kb), q1 = *(const float4*)(sC + kb + 4);
        bf16x8 f;
        f[0] = (bf16)bnrelu((float)raw[0], a0.x, q0.x); f[1] = (bf16)bnrelu((float)raw[1], a0.y, q0.y);
        f[2] = (bf16)bnrelu((float)raw[2], a0.z, q0.z); f[3] = (bf16)bnrelu((float)raw[3], a0.w, q0.w);
        f[4] = (bf16)bnrelu((float)raw[4], a1.x, q1.x); f[5] = (bf16)bnrelu((float)raw[5], a1.y, q1.y);
        f[6] = (bf16)bnrelu((float)raw[6], a1.z, q1.z); f[7] = (bf16)bnrelu((float)raw[7], a1.w, q1.w);
        af[rt] = f;
      }
    }
    bf16x8 bfr[8];
#pragma unroll
    for (int ct = 0; ct < 8; ++ct)
      bfr[ct] = *(const bf16x8*)(Wb + (size_t)(ct * 16 + lm) * HID + kb);
#pragma unroll
    for (int rt = 0; rt < 2; ++rt)
#pragma unroll
      for (int ct = 0; ct < 8; ++ct)
        acc[rt][ct] = __builtin_amdgcn_mfma_f32_16x16x32_bf16(af[rt], bfr[ct], acc[rt][ct], 0, 0, 0);
  }
#pragma unroll
  for (int ct = 0; ct < 8; ++ct) {
    int col = ct * 16 + lm;
    float ps = 0.f, pq = 0.f;
#pragma unroll
    for (int rt = 0; rt < 2; ++rt) {
#pragma unroll
      for (int i = 0; i < 4; ++i) {
        int row = rowbase + rt * 16 + lg * 4 + i;
        if (row < Nrows) {
          float v = acc[rt][ct][i];
          if (OUTF) Cf[(size_t)row * HID + col] = v;
          else      Cb[(size_t)row * HID + col] = (bf16)v;
          ps += v; pq = fmaf(v, v, pq);
        }
      }
    }
    ps += __shfl_xor(ps, 16, 64); ps += __shfl_xor(ps, 32, 64);
    pq += __shfl_xor(pq, 16, 64); pq += __shfl_xor(pq, 32, 64);
    if (lane < 16) { atomicAdd(&sSum[col], ps); atomicAdd(&sSq[col], pq); }
  }
  __syncthreads();
  if (tid < 128) {
    atomicAdd(&accumOut[tid], sSum[tid]);
    atomicAdd(&accumOut[128 + tid], sSq[tid]);
  }
}

// ---------------- stats of y=relu(a*x+c) + write Y bf16 ----------------
__global__ __launch_bounds__(256)
void stats1_k(const float* __restrict__ T, const float* __restrict__ acIn,
              const float* __restrict__ g, const float* __restrict__ b, float invN,
              float* __restrict__ accumOut, bf16* __restrict__ Y, int Nrows) {
  int col = threadIdx.x & 127, half = threadIdx.x >> 7;
  float mu = acIn[col] * invN;
  float var = fmaxf(acIn[128 + col] * invN - mu * mu, 0.f);
  float av = g[col] * rsqrtf(var + BN_EPS);
  float cv = fmaf(-av, mu, b[col]);
  float s = 0.f, sq = 0.f;
  for (int r = blockIdx.x * 2 + half; r < Nrows; r += gridDim.x * 2) {
    float x = T[(size_t)r * HID + col];
    x = fmaxf(fmaf(av, x, cv), 0.f);
    Y[(size_t)r * HID + col] = (bf16)x;
    s += x; sq = fmaf(x, x, sq);
  }
  __shared__ float sb[256], qb[256];
  sb[threadIdx.x] = s; qb[threadIdx.x] = sq;
  __syncthreads();
  if (half == 0) {
    s += sb[threadIdx.x + 128]; sq += qb[threadIdx.x + 128];
    atomicAdd(&accumOut[col], s); atomicAdd(&accumOut[128 + col], sq);
  }
}

// ---------------- fused link predictor (512 threads, 8 waves x 16-row stripes) ----------------
__global__ __launch_bounds__(512)
void pred_k(const float* __restrict__ T, const float* __restrict__ acIn,
            const float* __restrict__ g, const float* __restrict__ b, float invN,
            const int* __restrict__ ps, const int* __restrict__ pd,
            const int* __restrict__ ns, const int* __restrict__ nd,
            const bf16* __restrict__ W1b, const float* __restrict__ b1p,
            const bf16* __restrict__ W2b, const float* __restrict__ b2p,
            const float* __restrict__ w3, const float* __restrict__ b3,
            float* __restrict__ out, int Pn) {
  __shared__ bf16 At[128 * 128];
  __shared__ float sAp[128], sCp[128];
  int tid = threadIdx.x;
  if (tid < 128) {
    float mu = acIn[tid] * invN;
    float var = fmaxf(acIn[128 + tid] * invN - mu * mu, 0.f);
    float a = g[tid] * rsqrtf(var + BN_EPS);
    sAp[tid] = a; sCp[tid] = fmaf(-a, mu, b[tid]);
  }
  __syncthreads();
  int q0 = blockIdx.x * 128;
  {
    int r = tid >> 2;                 // 128 rows, 4 threads per row
    int q = q0 + r;
    int cb = (tid & 3) * 32;
    if (q < 2 * Pn) {
      int s, d;
      if (q < Pn) { s = ps[q]; d = pd[q]; } else { s = ns[q - Pn]; d = nd[q - Pn]; }
      const float* rs_ = T + (size_t)s * HID;
      const float* rd_ = T + (size_t)d * HID;
#pragma unroll
      for (int c = cb; c < cb + 32; c += 4) {
        float4 xs = *(const float4*)(rs_ + c);
        float4 xd = *(const float4*)(rd_ + c);
        float4 av = *(const float4*)(sAp + c);
        float4 cv = *(const float4*)(sCp + c);
        float t0 = bnrelu(xs.x, av.x, cv.x) * bnrelu(xd.x, av.x, cv.x);
        float t1 = bnrelu(xs.y, av.y, cv.y) * bnrelu(xd.y, av.y, cv.y);
        float t2 = bnrelu(xs.z, av.z, cv.z) * bnrelu(xd.z, av.z, cv.z);
        float t3 = bnrelu(xs.w, av.w, cv.w) * bnrelu(xd.w, av.w, cv.w);
        union { bf16 h[4]; unsigned long long u; } pk;
        pk.h[0] = (bf16)t0; pk.h[1] = (bf16)t1; pk.h[2] = (bf16)t2; pk.h[3] = (bf16)t3;
        unsigned addr = (unsigned)(r * 256 + c * 2);
        addr ^= (unsigned)((r & 7) << 4);
        *(unsigned long long*)((char*)At + addr) = pk.u;
      }
    } else {
#pragma unroll
      for (int c = cb; c < cb + 32; c += 4) {
        unsigned addr = (unsigned)(r * 256 + c * 2);
        addr ^= (unsigned)((r & 7) << 4);
        *(unsigned long long*)((char*)At + addr) = 0ull;
      }
    }
  }
  __syncthreads();
  int wv = tid >> 6, lane = tid & 63;
  int lm = lane & 15, lg = lane >> 4;
  const f32x4 vzero = {0.f, 0.f, 0.f, 0.f};
  f32x4 acc[8];
#pragma unroll
  for (int c = 0; c < 8; ++c) acc[c] = vzero;
  int rowA = wv * 16 + lm;          // wave-private 16-row stripe
  // ---- layer 1 ----
#pragma unroll
  for (int kk = 0; kk < 4; ++kk) {
    unsigned addr = (unsigned)(rowA * 256 + kk * 64 + lg * 16);
    addr ^= (unsigned)((rowA & 7) << 4);
    bf16x8 af = *(const bf16x8*)((char*)At + addr);
    bf16x8 bfr[8];
#pragma unroll
    for (int ct = 0; ct < 8; ++ct)
      bfr[ct] = *(const bf16x8*)(W1b + (size_t)(ct * 16 + lm) * HID + kk * 32 + lg * 8);
#pragma unroll
    for (int ct = 0; ct < 8; ++ct)
      acc[ct] = __builtin_amdgcn_mfma_f32_16x16x32_bf16(af, bfr[ct], acc[ct], 0, 0, 0);
  }
  __syncthreads();
#pragma unroll
  for (int ct = 0; ct < 8; ++ct) {
    int col = ct * 16 + lm;
    float bb = b1p[col];
#pragma unroll
    for (int i = 0; i < 4; ++i) {
      int row = wv * 16 + lg * 4 + i;
      float v = fmaxf(acc[ct][i] + bb, 0.f);
      unsigned addr = (unsigned)(row * 256 + col * 2);
      addr ^= (unsigned)((row & 7) << 4);
      *(bf16*)((char*)At + addr) = (bf16)v;
    }
  }
  __syncthreads();
  // ---- layer 2 ----
#pragma unroll
  for (int c = 0; c < 8; ++c) acc[c] = vzero;
#pragma unroll
  for (int kk = 0; kk < 4; ++kk) {
    unsigned addr = (unsigned)(rowA * 256 + kk * 64 + lg * 16);
    addr ^= (unsigned)((rowA & 7) << 4);
    bf16x8 af = *(const bf16x8*)((char*)At + addr);
    bf16x8 bfr[8];
#pragma unroll
    for (int ct = 0; ct < 8; ++ct)
      bfr[ct] = *(const bf16x8*)(W2b + (size_t)(ct * 16 + lm) * HID + kk * 32 + lg * 8);
#pragma unroll
    for (int ct = 0; ct < 8; ++ct)
      acc[ct] = __builtin_amdgcn_mfma_f32_16x16x32_bf16(af, bfr[ct], acc[ct], 0, 0, 0);
  }
  // ---- w3 dot + reduce ----
  float b2v[8], w3v[8];
#pragma unroll
  for (int ct = 0; ct < 8; ++ct) { b2v[ct] = b2p[ct * 16 + lm]; w3v[ct] = w3[ct * 16 + lm]; }
  float b3s = b3[0];
#pragma unroll
  for (int i = 0; i < 4; ++i) {
    float p = 0.f;
#pragma unroll
    for (int ct = 0; ct < 8; ++ct)
      p += fmaxf(acc[ct][i] + b2v[ct], 0.f) * w3v[ct];
    p += __shfl_xor(p, 1); p += __shfl_xor(p, 2);
    p += __shfl_xor(p, 4); p += __shfl_xor(p, 8);
    int row = wv * 16 + lg * 4 + i;
    int q = q0 + row;
    if (lm == 0 && q < 2 * Pn) out[q] = p + b3s;
  }
}

// ---------------- launcher ----------------
extern "C" void kernel_launch(void* const* d_in, const int* in_sizes, int n_in,
                              void* d_out, int out_size, void* d_ws, size_t ws_size,
                              hipStream_t stream) {
  const float* x  = (const float*)d_in[0];
  const int* src  = (const int*)d_in[1];
  const int* dst  = (const int*)d_in[2];
  const int* ps   = (const int*)d_in[3];
  const int* pd   = (const int*)d_in[4];
  const int* ns   = (const int*)d_in[5];
  const int* nd   = (const int*)d_in[6];
  const float* W0 = (const float*)d_in[7];
  const float* W1 = (const float*)d_in[8];
  const float* g_mlp   = (const float*)d_in[9];
  const float* b_mlp   = (const float*)d_in[10];
  const float* g_apply = (const float*)d_in[11];
  const float* b_apply = (const float*)d_in[12];
  const float* g_out   = (const float*)d_in[13];
  const float* b_out   = (const float*)d_in[14];
  const float* pW1 = (const float*)d_in[15];
  const float* pb1 = (const float*)d_in[16];
  const float* pW2 = (const float*)d_in[17];
  const float* pb2 = (const float*)d_in[18];
  const float* pW3 = (const float*)d_in[19];
  const float* pb3 = (const float*)d_in[20];
  float* out = (float*)d_out;

  const int N = in_sizes[0] / HID;
  const int E = in_sizes[1];
  const int P = in_sizes[3];
  const int NB2 = (N + PBW - 1) >> PSHIFT;

  char* w = (char*)d_ws;
  size_t off = 0;
  auto alloc = [&](size_t bytes) -> void* {
    void* p = w + off;
    off = (off + bytes + 255) & ~(size_t)255;
    return p;
  };
  bf16*  Z   = (bf16*)alloc((size_t)N * HID * 2);
  bf16*  TAb = (bf16*)alloc((size_t)N * HID * 2);
  float* TB  = (float*)alloc((size_t)N * HID * 4);
  bf16*  Yb  = (bf16*)alloc((size_t)N * HID * 2);
  bf16*  Xh  = (bf16*)alloc((size_t)N * HID * 2);
  int*   csr = (int*)alloc((size_t)E * 4);
  unsigned* ebuf2 = (unsigned*)alloc((size_t)E * 4);
  int*   row_start = (int*)alloc((size_t)(N + 1) * 4);
  size_t zoff = off;
  int*   cnt   = (int*)alloc((size_t)N * 4);
  float* accum = (float*)alloc(9 * 256 * 4);
  size_t zbytes = off - zoff;
  int*   bsum   = (int*)alloc(256 * 4);
  int*   bcur   = (int*)alloc(256 * 4);
  bf16*  Wb = (bf16*)alloc(8 * 16384 * 2);
  (void)ws_size; (void)n_in; (void)out_size;

  const int G = (N + 1023) / 1024;
  const float invN = 1.f / (float)N;

  hipMemsetAsync(w + zoff, 0, zbytes, stream);
  int gridE = (E + 255) / 256;
  hist_k<<<gridE, 256, 0, stream>>>(dst, cnt, E);
  scan1_k<<<G, 256, 0, stream>>>(cnt, bsum, N);
  scan2_k<<<1, 64, 0, stream>>>(bsum, G);
  scan3_k<<<G, 256, 0, stream>>>(cnt, bsum, row_start, N, E);
  initb_k<<<1, 256, 0, stream>>>(row_start, bcur, N, NB2);
  partb_k<<<(E + 2047) / 2048, 256, 0, stream>>>(src, dst, bcur, ebuf2, E, NB2);
  fillb_k<<<NB2, 512, 0, stream>>>(ebuf2, row_start, csr, N);
  wconv_k<<<128, 256, 0, stream>>>(W0, W1, pW1, pW2, Wb);
  xconv_k<<<(N * HID / 4 + 255) / 256, 256, 0, stream>>>(x, Xh, N * HID);

  int gridN4 = (N + 3) / 4;
  int gridG  = (N + 127) / 128;

  for (int l = 0; l < 3; ++l) {
    int s0 = l * 3 + 0, s1 = l * 3 + 1, s2 = l * 3 + 2;
    if (l == 0)
      agg_k<0><<<gridN4, 256, 0, stream>>>(Xh, nullptr, nullptr, nullptr, invN,
                                           row_start, csr, Z, N);
    else {
      int p2 = (l - 1) * 3 + 2;
      agg_k<1><<<gridN4, 256, 0, stream>>>(Yb,
                                           accum + p2 * 256, g_out + (l - 1) * HID, b_out + (l - 1) * HID,
                                           invN, row_start, csr, Z, N);
    }
    gemm_k<0, 0><<<gridG, 256, 0, stream>>>(Z, nullptr, nullptr, nullptr, invN,
                                            Wb + (size_t)l * 16384, TAb, nullptr,
                                            accum + s0 * 256, N);
    gemm_k<1, 1><<<gridG, 256, 0, stream>>>(TAb, accum + s0 * 256, g_mlp + l * HID, b_mlp + l * HID,
                                            invN, Wb + (size_t)(3 + l) * 16384, nullptr, TB,
                                            accum + s1 * 256, N);
    if (l < 2)
      stats1_k<<<512, 256, 0, stream>>>(TB, accum + s1 * 256, g_apply + l * HID, b_apply + l * HID,
                                        invN, accum + s2 * 256, Yb, N);
  }
  int gridP = (2 * P + 127) / 128;
  pred_k<<<gridP, 512, 0, stream>>>(TB, accum + 7 * 256, g_apply + 2 * HID, b_apply + 2 * HID, invN,
                                    ps, pd, ns, nd,
                                    Wb + (size_t)6 * 16384, pb1,
                                    Wb + (size_t)7 * 16384, pb2,
                                    pW3, pb3, out, P);
}

// Round 9
// 892.114 us; speedup vs baseline: 1.0693x; 1.0693x over previous
//
#include <hip/hip_runtime.h>

#define HID 128
#define BN_EPS 1e-5f
#define PSHIFT 9
#define PBW 512

typedef __bf16 bf16;
typedef __attribute__((ext_vector_type(8))) __bf16 bf16x8;
typedef __attribute__((ext_vector_type(2))) __bf16 bf16x2;
typedef __attribute__((ext_vector_type(4))) float f32x4;

__device__ __forceinline__ float bnrelu(float x, float a, float c) {
  return fmaxf(fmaf(a, x, c), 0.f);
}

// ---------------- per-node histogram ----------------
__global__ void hist_k(const int* __restrict__ dst, int* __restrict__ cnt, int E) {
  int i = blockIdx.x * blockDim.x + threadIdx.x;
  if (i < E) atomicAdd(&cnt[dst[i]], 1);
}

// block partial sums (1024 elems / block)
__global__ __launch_bounds__(256)
void scan1_k(const int* __restrict__ cnt, int* __restrict__ bsum, int Nn) {
  __shared__ int red[4];
  int tid = threadIdx.x;
  int base = blockIdx.x * 1024;
  int s = 0;
#pragma unroll
  for (int u = 0; u < 4; ++u) {
    int i = base + u * 256 + tid;
    if (i < Nn) s += cnt[i];
  }
#pragma unroll
  for (int d = 1; d < 64; d <<= 1) s += __shfl_xor(s, d, 64);
  int lane = tid & 63, wv = tid >> 6;
  if (lane == 0) red[wv] = s;
  __syncthreads();
  if (tid == 0) bsum[blockIdx.x] = red[0] + red[1] + red[2] + red[3];
}

// exclusive scan of block sums, in place (single wave)
__global__ void scan2_k(int* __restrict__ bsum, int G) {
  int lane = threadIdx.x;
  int carry = 0;
  for (int base = 0; base < G; base += 64) {
    int i = base + lane;
    int v = (i < G) ? bsum[i] : 0;
    int x = v;
#pragma unroll
    for (int d = 1; d < 64; d <<= 1) { int t = __shfl_up(x, d, 64); if (lane >= d) x += t; }
    if (i < G) bsum[i] = carry + x - v;
    carry += __shfl(x, 63, 64);
  }
}

// final scan: row_start
__global__ __launch_bounds__(256)
void scan3_k(const int* __restrict__ cnt, const int* __restrict__ boff,
             int* __restrict__ row_start, int Nn, int E) {
  __shared__ int wtot[4];
  int tid = threadIdx.x, lane = tid & 63, wv = tid >> 6;
  int i0 = blockIdx.x * 1024 + tid * 4;
  int t0 = 0, t1 = 0, t2 = 0, t3 = 0;
  if (i0 + 3 < Nn) {
    int4 v = *(const int4*)(cnt + i0);
    t0 = v.x; t1 = v.y; t2 = v.z; t3 = v.w;
  } else {
    if (i0     < Nn) t0 = cnt[i0];
    if (i0 + 1 < Nn) t1 = cnt[i0 + 1];
    if (i0 + 2 < Nn) t2 = cnt[i0 + 2];
    if (i0 + 3 < Nn) t3 = cnt[i0 + 3];
  }
  int tsum = t0 + t1 + t2 + t3;
  int x = tsum;
#pragma unroll
  for (int d = 1; d < 64; d <<= 1) { int t = __shfl_up(x, d, 64); if (lane >= d) x += t; }
  if (lane == 63) wtot[wv] = x;
  __syncthreads();
  int wo = 0;
  for (int k = 0; k < wv; ++k) wo += wtot[k];
  int base = boff[blockIdx.x] + wo + x - tsum;
  if (i0     < Nn) row_start[i0] = base;
  if (i0 + 1 < Nn) row_start[i0 + 1] = base + t0;
  if (i0 + 2 < Nn) row_start[i0 + 2] = base + t0 + t1;
  if (i0 + 3 < Nn) row_start[i0 + 3] = base + t0 + t1 + t2;
  if (blockIdx.x == 0 && tid == 0) row_start[Nn] = E;
}

// ---------------- coarse-bucket cursor init (bucket = PBW nodes) ----------------
__global__ void initb_k(const int* __restrict__ row_start, int* __restrict__ bcur,
                        int Nn, int NB2) {
  int i = threadIdx.x;
  if (i < NB2) {
    int n = i << PSHIFT; if (n > Nn) n = Nn;
    bcur[i] = row_start[n];
  }
}

// ---------------- partition edges into PBW-node buckets, packed (dl<<17)|src ----------------
__global__ __launch_bounds__(256)
void partb_k(const int* __restrict__ src, const int* __restrict__ dst,
             int* __restrict__ bcur, unsigned* __restrict__ ebuf2, int E, int NB2) {
  __shared__ int lcnt[256], gbase[256], lcur[256];
  int tid = threadIdx.x;
  lcnt[tid] = 0; lcur[tid] = 0;
  __syncthreads();
  int base = blockIdx.x * 2048;
  int ok[8]; unsigned pk[8]; int bk[8];
#pragma unroll
  for (int u = 0; u < 8; ++u) {
    int e = base + u * 256 + tid;
    if (e < E) {
      int s = src[e], d = dst[e];
      ok[u] = 1; bk[u] = d >> PSHIFT;
      pk[u] = ((unsigned)(d & (PBW - 1)) << 17) | (unsigned)s;
      atomicAdd(&lcnt[bk[u]], 1);
    } else ok[u] = 0;
  }
  __syncthreads();
  if (tid < NB2 && lcnt[tid]) gbase[tid] = atomicAdd(&bcur[tid], lcnt[tid]);
  __syncthreads();
#pragma unroll
  for (int u = 0; u < 8; ++u) if (ok[u]) {
    int sl = atomicAdd(&lcur[bk[u]], 1);
    ebuf2[gbase[bk[u]] + sl] = pk[u];
  }
}

// ---------------- bucket -> CSR (one block owns one PBW-node bucket) ----------------
__global__ __launch_bounds__(512)
void fillb_k(const unsigned* __restrict__ ebuf2, const int* __restrict__ row_start,
             int* __restrict__ csr, int Nn) {
  __shared__ int ncur[PBW];
  int tid = threadIdx.x;
  if (tid < PBW) ncur[tid] = 0;
  __syncthreads();
  int nb0 = blockIdx.x << PSHIFT;
  int hi = nb0 + PBW; if (hi > Nn) hi = Nn;
  int beg = row_start[nb0], end = row_start[hi];
  for (int e = beg + tid; e < end; e += 512) {
    unsigned v = ebuf2[e];
    int dl = v >> 17, s = (int)(v & 0x1FFFF);
    int p = atomicAdd(&ncur[dl], 1);
    csr[row_start[nb0 + dl] + p] = s;
  }
}

// ---------------- weight convert to bf16 ----------------
__global__ __launch_bounds__(256)
void wconv_k(const float* __restrict__ W0, const float* __restrict__ W1,
             const float* __restrict__ pW1, const float* __restrict__ pW2,
             bf16* __restrict__ Wb) {
  int idx = (blockIdx.x * 256 + threadIdx.x) * 4;
  int seg = idx >> 14, loc = idx & 16383;
  const float* srcp = seg < 3 ? W0 + (size_t)seg * 16384
                    : seg < 6 ? W1 + (size_t)(seg - 3) * 16384
                    : seg == 6 ? pW1 : pW2;
  float4 v = *(const float4*)(srcp + loc);
  union { bf16 h[4]; unsigned long long u; } pk;
  pk.h[0] = (bf16)v.x; pk.h[1] = (bf16)v.y; pk.h[2] = (bf16)v.z; pk.h[3] = (bf16)v.w;
  *(unsigned long long*)(Wb + idx) = pk.u;
}

// ---------------- x -> bf16 convert ----------------
__global__ __launch_bounds__(256)
void xconv_k(const float* __restrict__ X, bf16* __restrict__ Xh, int total) {
  int idx = (blockIdx.x * 256 + threadIdx.x) * 4;
  if (idx >= total) return;
  float4 v = *(const float4*)(X + idx);
  union { bf16 h[4]; unsigned long long u; } pk;
  pk.h[0] = (bf16)v.x; pk.h[1] = (bf16)v.y; pk.h[2] = (bf16)v.z; pk.h[3] = (bf16)v.w;
  *(unsigned long long*)(Xh + idx) = pk.u;
}

// ---------------- aggregation from bf16 source, unroll-8 ----------------
template<int MODE>
__global__ __launch_bounds__(256)
void agg_k(const bf16* __restrict__ Hh,
           const float* __restrict__ ac, const float* __restrict__ g, const float* __restrict__ b,
           float invN,
           const int* __restrict__ row_start, const int* __restrict__ csr,
           bf16* __restrict__ Z, int Nn) {
  __shared__ float sA[128], sC[128];
  int tid = threadIdx.x;
  if (MODE) {
    if (tid < 128) {
      float mu = ac[tid] * invN;
      float var = fmaxf(ac[128 + tid] * invN - mu * mu, 0.f);
      float a = g[tid] * rsqrtf(var + BN_EPS);
      sA[tid] = a; sC[tid] = fmaf(-a, mu, b[tid]);
    }
    __syncthreads();
  }
  int wv = tid >> 6, lane = tid & 63;
  int n = blockIdx.x * 4 + wv;
  if (n >= Nn) return;
  int c0 = lane * 2;
  float Ax = 0, Ay = 0, Cx = 0, Cy = 0;
  if (MODE) { Ax = sA[c0]; Ay = sA[c0 + 1]; Cx = sC[c0]; Cy = sC[c0 + 1]; }
  int beg = row_start[n], end = row_start[n + 1];
  bf16x2 hn = *(const bf16x2*)(Hh + (size_t)n * HID + c0);
  float inv = 1.f / fmaxf((float)(end - beg), 1.f);
  float ax0 = 0, ay0 = 0, ax1 = 0, ay1 = 0, ax2 = 0, ay2 = 0, ax3 = 0, ay3 = 0;
  int j = beg;
  for (; j + 8 <= end; j += 8) {
    int s0 = csr[j], s1 = csr[j + 1], s2 = csr[j + 2], s3 = csr[j + 3];
    int s4 = csr[j + 4], s5 = csr[j + 5], s6 = csr[j + 6], s7 = csr[j + 7];
    bf16x2 v0 = *(const bf16x2*)(Hh + (size_t)s0 * HID + c0);
    bf16x2 v1 = *(const bf16x2*)(Hh + (size_t)s1 * HID + c0);
    bf16x2 v2 = *(const bf16x2*)(Hh + (size_t)s2 * HID + c0);
    bf16x2 v3 = *(const bf16x2*)(Hh + (size_t)s3 * HID + c0);
    bf16x2 v4 = *(const bf16x2*)(Hh + (size_t)s4 * HID + c0);
    bf16x2 v5 = *(const bf16x2*)(Hh + (size_t)s5 * HID + c0);
    bf16x2 v6 = *(const bf16x2*)(Hh + (size_t)s6 * HID + c0);
    bf16x2 v7 = *(const bf16x2*)(Hh + (size_t)s7 * HID + c0);
    float x0 = (float)v0[0], y0 = (float)v0[1], x1 = (float)v1[0], y1 = (float)v1[1];
    float x2 = (float)v2[0], y2 = (float)v2[1], x3 = (float)v3[0], y3 = (float)v3[1];
    float x4 = (float)v4[0], y4 = (float)v4[1], x5 = (float)v5[0], y5 = (float)v5[1];
    float x6 = (float)v6[0], y6 = (float)v6[1], x7 = (float)v7[0], y7 = (float)v7[1];
    if (MODE) {
      x0 = bnrelu(x0, Ax, Cx); y0 = bnrelu(y0, Ay, Cy);
      x1 = bnrelu(x1, Ax, Cx); y1 = bnrelu(y1, Ay, Cy);
      x2 = bnrelu(x2, Ax, Cx); y2 = bnrelu(y2, Ay, Cy);
      x3 = bnrelu(x3, Ax, Cx); y3 = bnrelu(y3, Ay, Cy);
      x4 = bnrelu(x4, Ax, Cx); y4 = bnrelu(y4, Ay, Cy);
      x5 = bnrelu(x5, Ax, Cx); y5 = bnrelu(y5, Ay, Cy);
      x6 = bnrelu(x6, Ax, Cx); y6 = bnrelu(y6, Ay, Cy);
      x7 = bnrelu(x7, Ax, Cx); y7 = bnrelu(y7, Ay, Cy);
    }
    ax0 += x0; ay0 += y0; ax1 += x1; ay1 += y1;
    ax2 += x2; ay2 += y2; ax3 += x3; ay3 += y3;
    ax0 += x4; ay0 += y4; ax1 += x5; ay1 += y5;
    ax2 += x6; ay2 += y6; ax3 += x7; ay3 += y7;
  }
  for (; j < end; ++j) {
    int s = csr[j];
    bf16x2 v = *(const bf16x2*)(Hh + (size_t)s * HID + c0);
    float vx = (float)v[0], vy = (float)v[1];
    if (MODE) { vx = bnrelu(vx, Ax, Cx); vy = bnrelu(vy, Ay, Cy); }
    ax0 += vx; ay0 += vy;
  }
  float ax = (ax0 + ax1) + (ax2 + ax3);
  float ay = (ay0 + ay1) + (ay2 + ay3);
  float hx = (float)hn[0], hy = (float)hn[1];
  if (MODE) { hx = bnrelu(hx, Ax, Cx); hy = bnrelu(hy, Ay, Cy); }
  float zx = hx + ax * inv, zy = hy + ay * inv;
  union { bf16 h[2]; unsigned u; } pk;
  pk.h[0] = (bf16)zx; pk.h[1] = (bf16)zy;
  *(unsigned*)((char*)Z + ((size_t)n * HID + c0) * 2) = pk.u;
}

// ---------------- GEMM: C = A @ W^T, bf16 A and weights, fused column stats ----------------
template<int AMODE, int OUTF>
__global__ __launch_bounds__(256)
void gemm_k(const bf16* __restrict__ Asrc,
            const float* __restrict__ acIn, const float* __restrict__ g, const float* __restrict__ b,
            float invN,
            const bf16* __restrict__ Wb, bf16* __restrict__ Cb, float* __restrict__ Cf,
            float* __restrict__ accumOut, int Nrows) {
  __shared__ float sA[128], sC[128], sSum[128], sSq[128];
  int tid = threadIdx.x;
  if (tid < 128) {
    sSum[tid] = 0.f; sSq[tid] = 0.f;
    if (AMODE) {
      float mu = acIn[tid] * invN;
      float var = fmaxf(acIn[128 + tid] * invN - mu * mu, 0.f);
      float a = g[tid] * rsqrtf(var + BN_EPS);
      sA[tid] = a; sC[tid] = fmaf(-a, mu, b[tid]);
    }
  }
  __syncthreads();
  int wv = tid >> 6, lane = tid & 63;
  int lm = lane & 15, lg = lane >> 4;
  int rowbase = blockIdx.x * 128 + wv * 32;
  f32x4 acc[2][8] = {};
#pragma unroll
  for (int kk = 0; kk < 4; ++kk) {
    int kb = kk * 32 + lg * 8;
    bf16x8 af[2];
#pragma unroll
    for (int rt = 0; rt < 2; ++rt) {
      int row = rowbase + rt * 16 + lm; if (row > Nrows - 1) row = Nrows - 1;
      bf16x8 raw = *(const bf16x8*)(Asrc + (size_t)row * HID + kb);
      if (AMODE == 0) {
        af[rt] = raw;
      } else {
        float4 a0 = *(const float4*)(sA + kb), a1 = *(const float4*)(sA + kb + 4);
        float4 q0 = *(const float4*)(sC + kb), q1 = *(const float4*)(sC + kb + 4);
        bf16x8 f;
        f[0] = (bf16)bnrelu((float)raw[0], a0.x, q0.x); f[1] = (bf16)bnrelu((float)raw[1], a0.y, q0.y);
        f[2] = (bf16)bnrelu((float)raw[2], a0.z, q0.z); f[3] = (bf16)bnrelu((float)raw[3], a0.w, q0.w);
        f[4] = (bf16)bnrelu((float)raw[4], a1.x, q1.x); f[5] = (bf16)bnrelu((float)raw[5], a1.y, q1.y);
        f[6] = (bf16)bnrelu((float)raw[6], a1.z, q1.z); f[7] = (bf16)bnrelu((float)raw[7], a1.w, q1.w);
        af[rt] = f;
      }
    }
    bf16x8 bfr[8];
#pragma unroll
    for (int ct = 0; ct < 8; ++ct)
      bfr[ct] = *(const bf16x8*)(Wb + (size_t)(ct * 16 + lm) * HID + kb);
#pragma unroll
    for (int rt = 0; rt < 2; ++rt)
#pragma unroll
      for (int ct = 0; ct < 8; ++ct)
        acc[rt][ct] = __builtin_amdgcn_mfma_f32_16x16x32_bf16(af[rt], bfr[ct], acc[rt][ct], 0, 0, 0);
  }
#pragma unroll
  for (int ct = 0; ct < 8; ++ct) {
    int col = ct * 16 + lm;
    float ps = 0.f, pq = 0.f;
#pragma unroll
    for (int rt = 0; rt < 2; ++rt) {
#pragma unroll
      for (int i = 0; i < 4; ++i) {
        int row = rowbase + rt * 16 + lg * 4 + i;
        if (row < Nrows) {
          float v = acc[rt][ct][i];
          if (OUTF) Cf[(size_t)row * HID + col] = v;
          else      Cb[(size_t)row * HID + col] = (bf16)v;
          ps += v; pq = fmaf(v, v, pq);
        }
      }
    }
    ps += __shfl_xor(ps, 16, 64); ps += __shfl_xor(ps, 32, 64);
    pq += __shfl_xor(pq, 16, 64); pq += __shfl_xor(pq, 32, 64);
    if (lane < 16) { atomicAdd(&sSum[col], ps); atomicAdd(&sSq[col], pq); }
  }
  __syncthreads();
  if (tid < 128) {
    atomicAdd(&accumOut[tid], sSum[tid]);
    atomicAdd(&accumOut[128 + tid], sSq[tid]);
  }
}

// ---------------- stats of y=relu(a*x+c) + write Y bf16 ----------------
__global__ __launch_bounds__(256)
void stats1_k(const float* __restrict__ T, const float* __restrict__ acIn,
              const float* __restrict__ g, const float* __restrict__ b, float invN,
              float* __restrict__ accumOut, bf16* __restrict__ Y, int Nrows) {
  int col = threadIdx.x & 127, half = threadIdx.x >> 7;
  float mu = acIn[col] * invN;
  float var = fmaxf(acIn[128 + col] * invN - mu * mu, 0.f);
  float av = g[col] * rsqrtf(var + BN_EPS);
  float cv = fmaf(-av, mu, b[col]);
  float s = 0.f, sq = 0.f;
  for (int r = blockIdx.x * 2 + half; r < Nrows; r += gridDim.x * 2) {
    float x = T[(size_t)r * HID + col];
    x = fmaxf(fmaf(av, x, cv), 0.f);
    Y[(size_t)r * HID + col] = (bf16)x;
    s += x; sq = fmaf(x, x, sq);
  }
  __shared__ float sb[256], qb[256];
  sb[threadIdx.x] = s; qb[threadIdx.x] = sq;
  __syncthreads();
  if (half == 0) {
    s += sb[threadIdx.x + 128]; sq += qb[threadIdx.x + 128];
    atomicAdd(&accumOut[col], s); atomicAdd(&accumOut[128 + col], sq);
  }
}

// ---------------- fused link predictor: direct-gather A fragments (no input staging) ----------------
__global__ __launch_bounds__(256)
void pred_k(const float* __restrict__ T, const float* __restrict__ acIn,
            const float* __restrict__ g, const float* __restrict__ b, float invN,
            const int* __restrict__ ps, const int* __restrict__ pd,
            const int* __restrict__ ns, const int* __restrict__ nd,
            const bf16* __restrict__ W1b, const float* __restrict__ b1p,
            const bf16* __restrict__ W2b, const float* __restrict__ b2p,
            const float* __restrict__ w3, const float* __restrict__ b3,
            float* __restrict__ out, int Pn) {
  __shared__ bf16 At[128 * 128];   // layer1->layer2 redistribution only
  __shared__ float sAp[128], sCp[128];
  int tid = threadIdx.x;
  if (tid < 128) {
    float mu = acIn[tid] * invN;
    float var = fmaxf(acIn[128 + tid] * invN - mu * mu, 0.f);
    float a = g[tid] * rsqrtf(var + BN_EPS);
    sAp[tid] = a; sCp[tid] = fmaf(-a, mu, b[tid]);
  }
  __syncthreads();
  int wv = tid >> 6, lane = tid & 63;
  int lm = lane & 15, lg = lane >> 4;
  int q0 = blockIdx.x * 128;
  const float* rsp[2]; const float* rdp[2];
#pragma unroll
  for (int rt = 0; rt < 2; ++rt) {
    int q = q0 + wv * 32 + rt * 16 + lm;
    if (q >= 2 * Pn) q = 2 * Pn - 1;   // clamped rows never stored
    int s, d;
    if (q < Pn) { s = ps[q]; d = pd[q]; } else { s = ns[q - Pn]; d = nd[q - Pn]; }
    rsp[rt] = T + (size_t)s * HID;
    rdp[rt] = T + (size_t)d * HID;
  }
  const f32x4 vzero = {0.f, 0.f, 0.f, 0.f};
  f32x4 acc[2][8];
#pragma unroll
  for (int r = 0; r < 2; ++r) for (int c = 0; c < 8; ++c) acc[r][c] = vzero;
  // ---- layer 1: A fragments gathered directly from T ----
#pragma unroll
  for (int kk = 0; kk < 4; ++kk) {
    int kb = kk * 32 + lg * 8;
    float4 a0 = *(const float4*)(sAp + kb), a1 = *(const float4*)(sAp + kb + 4);
    float4 c0 = *(const float4*)(sCp + kb), c1 = *(const float4*)(sCp + kb + 4);
    bf16x8 af[2];
#pragma unroll
    for (int rt = 0; rt < 2; ++rt) {
      float4 xs0 = *(const float4*)(rsp[rt] + kb), xs1 = *(const float4*)(rsp[rt] + kb + 4);
      float4 xd0 = *(const float4*)(rdp[rt] + kb), xd1 = *(const float4*)(rdp[rt] + kb + 4);
      bf16x8 f;
      f[0] = (bf16)(bnrelu(xs0.x, a0.x, c0.x) * bnrelu(xd0.x, a0.x, c0.x));
      f[1] = (bf16)(bnrelu(xs0.y, a0.y, c0.y) * bnrelu(xd0.y, a0.y, c0.y));
      f[2] = (bf16)(bnrelu(xs0.z, a0.z, c0.z) * bnrelu(xd0.z, a0.z, c0.z));
      f[3] = (bf16)(bnrelu(xs0.w, a0.w, c0.w) * bnrelu(xd0.w, a0.w, c0.w));
      f[4] = (bf16)(bnrelu(xs1.x, a1.x, c1.x) * bnrelu(xd1.x, a1.x, c1.x));
      f[5] = (bf16)(bnrelu(xs1.y, a1.y, c1.y) * bnrelu(xd1.y, a1.y, c1.y));
      f[6] = (bf16)(bnrelu(xs1.z, a1.z, c1.z) * bnrelu(xd1.z, a1.z, c1.z));
      f[7] = (bf16)(bnrelu(xs1.w, a1.w, c1.w) * bnrelu(xd1.w, a1.w, c1.w));
      af[rt] = f;
    }
    bf16x8 bfr[8];
#pragma unroll
    for (int ct = 0; ct < 8; ++ct)
      bfr[ct] = *(const bf16x8*)(W1b + (size_t)(ct * 16 + lm) * HID + kb);
#pragma unroll
    for (int rt = 0; rt < 2; ++rt)
#pragma unroll
      for (int ct = 0; ct < 8; ++ct)
        acc[rt][ct] = __builtin_amdgcn_mfma_f32_16x16x32_bf16(af[rt], bfr[ct], acc[rt][ct], 0, 0, 0);
  }
  // ---- epilogue 1 -> At (swizzled) ----
#pragma unroll
  for (int rt = 0; rt < 2; ++rt)
#pragma unroll
    for (int ct = 0; ct < 8; ++ct) {
      int col = ct * 16 + lm;
      float bb = b1p[col];
#pragma unroll
      for (int i = 0; i < 4; ++i) {
        int row = wv * 32 + rt * 16 + lg * 4 + i;
        float v = fmaxf(acc[rt][ct][i] + bb, 0.f);
        unsigned addr = (unsigned)(row * 256 + col * 2);
        addr ^= (unsigned)((row & 7) << 4);
        *(bf16*)((char*)At + addr) = (bf16)v;
      }
    }
  __syncthreads();
  // ---- layer 2 ----
#pragma unroll
  for (int r = 0; r < 2; ++r) for (int c = 0; c < 8; ++c) acc[r][c] = vzero;
#pragma unroll
  for (int kk = 0; kk < 4; ++kk) {
    bf16x8 af[2];
#pragma unroll
    for (int rt = 0; rt < 2; ++rt) {
      int row = wv * 32 + rt * 16 + lm;
      unsigned addr = (unsigned)(row * 256 + kk * 64 + lg * 16);
      addr ^= (unsigned)((row & 7) << 4);
      af[rt] = *(const bf16x8*)((char*)At + addr);
    }
    bf16x8 bfr[8];
#pragma unroll
    for (int ct = 0; ct < 8; ++ct)
      bfr[ct] = *(const bf16x8*)(W2b + (size_t)(ct * 16 + lm) * HID + kk * 32 + lg * 8);
#pragma unroll
    for (int rt = 0; rt < 2; ++rt)
#pragma unroll
      for (int ct = 0; ct < 8; ++ct)
        acc[rt][ct] = __builtin_amdgcn_mfma_f32_16x16x32_bf16(af[rt], bfr[ct], acc[rt][ct], 0, 0, 0);
  }
  // ---- w3 dot + reduce ----
  float b2v[8], w3v[8];
#pragma unroll
  for (int ct = 0; ct < 8; ++ct) { b2v[ct] = b2p[ct * 16 + lm]; w3v[ct] = w3[ct * 16 + lm]; }
  float b3s = b3[0];
#pragma unroll
  for (int rt = 0; rt < 2; ++rt) {
#pragma unroll
    for (int i = 0; i < 4; ++i) {
      float p = 0.f;
#pragma unroll
      for (int ct = 0; ct < 8; ++ct)
        p += fmaxf(acc[rt][ct][i] + b2v[ct], 0.f) * w3v[ct];
      p += __shfl_xor(p, 1); p += __shfl_xor(p, 2);
      p += __shfl_xor(p, 4); p += __shfl_xor(p, 8);
      int row = wv * 32 + rt * 16 + lg * 4 + i;
      int q = q0 + row;
      if (lm == 0 && q < 2 * Pn) out[q] = p + b3s;
    }
  }
}

// ---------------- launcher ----------------
extern "C" void kernel_launch(void* const* d_in, const int* in_sizes, int n_in,
                              void* d_out, int out_size, void* d_ws, size_t ws_size,
                              hipStream_t stream) {
  const float* x  = (const float*)d_in[0];
  const int* src  = (const int*)d_in[1];
  const int* dst  = (const int*)d_in[2];
  const int* ps   = (const int*)d_in[3];
  const int* pd   = (const int*)d_in[4];
  const int* ns   = (const int*)d_in[5];
  const int* nd   = (const int*)d_in[6];
  const float* W0 = (const float*)d_in[7];
  const float* W1 = (const float*)d_in[8];
  const float* g_mlp   = (const float*)d_in[9];
  const float* b_mlp   = (const float*)d_in[10];
  const float* g_apply = (const float*)d_in[11];
  const float* b_apply = (const float*)d_in[12];
  const float* g_out   = (const float*)d_in[13];
  const float* b_out   = (const float*)d_in[14];
  const float* pW1 = (const float*)d_in[15];
  const float* pb1 = (const float*)d_in[16];
  const float* pW2 = (const float*)d_in[17];
  const float* pb2 = (const float*)d_in[18];
  const float* pW3 = (const float*)d_in[19];
  const float* pb3 = (const float*)d_in[20];
  float* out = (float*)d_out;

  const int N = in_sizes[0] / HID;
  const int E = in_sizes[1];
  const int P = in_sizes[3];
  const int NB2 = (N + PBW - 1) >> PSHIFT;

  char* w = (char*)d_ws;
  size_t off = 0;
  auto alloc = [&](size_t bytes) -> void* {
    void* p = w + off;
    off = (off + bytes + 255) & ~(size_t)255;
    return p;
  };
  bf16*  Z   = (bf16*)alloc((size_t)N * HID * 2);
  bf16*  TAb = (bf16*)alloc((size_t)N * HID * 2);
  float* TB  = (float*)alloc((size_t)N * HID * 4);
  bf16*  Yb  = (bf16*)alloc((size_t)N * HID * 2);
  bf16*  Xh  = (bf16*)alloc((size_t)N * HID * 2);
  int*   csr = (int*)alloc((size_t)E * 4);
  unsigned* ebuf2 = (unsigned*)alloc((size_t)E * 4);
  int*   row_start = (int*)alloc((size_t)(N + 1) * 4);
  size_t zoff = off;
  int*   cnt   = (int*)alloc((size_t)N * 4);
  float* accum = (float*)alloc(9 * 256 * 4);
  size_t zbytes = off - zoff;
  int*   bsum   = (int*)alloc(256 * 4);
  int*   bcur   = (int*)alloc(256 * 4);
  bf16*  Wb = (bf16*)alloc(8 * 16384 * 2);
  (void)ws_size; (void)n_in; (void)out_size;

  const int G = (N + 1023) / 1024;
  const float invN = 1.f / (float)N;

  hipMemsetAsync(w + zoff, 0, zbytes, stream);
  int gridE = (E + 255) / 256;
  hist_k<<<gridE, 256, 0, stream>>>(dst, cnt, E);
  scan1_k<<<G, 256, 0, stream>>>(cnt, bsum, N);
  scan2_k<<<1, 64, 0, stream>>>(bsum, G);
  scan3_k<<<G, 256, 0, stream>>>(cnt, bsum, row_start, N, E);
  initb_k<<<1, 256, 0, stream>>>(row_start, bcur, N, NB2);
  partb_k<<<(E + 2047) / 2048, 256, 0, stream>>>(src, dst, bcur, ebuf2, E, NB2);
  fillb_k<<<NB2, 512, 0, stream>>>(ebuf2, row_start, csr, N);
  wconv_k<<<128, 256, 0, stream>>>(W0, W1, pW1, pW2, Wb);
  xconv_k<<<(N * HID / 4 + 255) / 256, 256, 0, stream>>>(x, Xh, N * HID);

  int gridN4 = (N + 3) / 4;
  int gridG  = (N + 127) / 128;

  for (int l = 0; l < 3; ++l) {
    int s0 = l * 3 + 0, s1 = l * 3 + 1, s2 = l * 3 + 2;
    if (l == 0)
      agg_k<0><<<gridN4, 256, 0, stream>>>(Xh, nullptr, nullptr, nullptr, invN,
                                           row_start, csr, Z, N);
    else {
      int p2 = (l - 1) * 3 + 2;
      agg_k<1><<<gridN4, 256, 0, stream>>>(Yb,
                                           accum + p2 * 256, g_out + (l - 1) * HID, b_out + (l - 1) * HID,
                                           invN, row_start, csr, Z, N);
    }
    gemm_k<0, 0><<<gridG, 256, 0, stream>>>(Z, nullptr, nullptr, nullptr, invN,
                                            Wb + (size_t)l * 16384, TAb, nullptr,
                                            accum + s0 * 256, N);
    gemm_k<1, 1><<<gridG, 256, 0, stream>>>(TAb, accum + s0 * 256, g_mlp + l * HID, b_mlp + l * HID,
                                            invN, Wb + (size_t)(3 + l) * 16384, nullptr, TB,
                                            accum + s1 * 256, N);
    if (l < 2)
      stats1_k<<<512, 256, 0, stream>>>(TB, accum + s1 * 256, g_apply + l * HID, b_apply + l * HID,
                                        invN, accum + s2 * 256, Yb, N);
  }
  int gridP = (2 * P + 127) / 128;
  pred_k<<<gridP, 256, 0, stream>>>(TB, accum + 7 * 256, g_apply + 2 * HID, b_apply + 2 * HID, invN,
                                    ps, pd, ns, nd,
                                    Wb + (size_t)6 * 16384, pb1,
                                    Wb + (size_t)7 * 16384, pb2,
                                    pW3, pb3, out, P);
}